// Round 6
// baseline (1516.242 us; speedup 1.0000x reference)
//
#include <hip/hip_runtime.h>
#include <hip/hip_bf16.h>
#include <math.h>

#define Bz 8
#define Sz 1024
#define INz 128
#define Ez 512
#define Hz 8
#define HDz 64
#define FFz 2048
#define Lz 4
#define Nz (Bz*Sz)   // 8192
#define EPSf 1e-5f

typedef __attribute__((ext_vector_type(8))) short short8;
typedef __attribute__((ext_vector_type(4))) float floatx4;
#define MFMA16(a,b,c) __builtin_amdgcn_mfma_f32_16x16x32_bf16(a,b,c,0,0,0)

typedef __hip_bfloat16 bf16;

__device__ inline float b2f(bf16 v) { return __bfloat162float(v); }
__device__ inline bf16 f2b(float v) { return __float2bfloat16(v); }

// async 16B/lane global->LDS copy. lds base must be wave-uniform; HW adds lane*16.
__device__ inline void gll16(const bf16* g, bf16* l) {
  __builtin_amdgcn_global_load_lds(
      (const __attribute__((address_space(1))) unsigned int*)g,
      (__attribute__((address_space(3))) unsigned int*)l, 16, 0, 0);
}

// ---------------- fp32 -> bf16 cast
__global__ __launch_bounds__(256) void cast_f2b(const float* __restrict__ in,
    bf16* __restrict__ out, int n)
{
  int i = blockIdx.x * 256 + threadIdx.x;
  if (i < n) out[i] = f2b(in[i]);
}

// ---------------- bf16 MFMA NT GEMM, m97-style async staging, batched
// C[M,N] = A[M,K] @ Wm[N,K]^T (+bias) (relu?)  — batch z via element strides
__global__ __launch_bounds__(256) void gemm_bt(
    const bf16* __restrict__ A, const bf16* __restrict__ Wm,
    const float* __restrict__ bias, float* __restrict__ Cf,
    bf16* __restrict__ Cb, int M, int N, int K,
    long sA, long sW, long sC, int relu)
{
  int z = blockIdx.z;
  A  += (size_t)z * sA;
  Wm += (size_t)z * sW;
  size_t cbase = (size_t)z * sC;
  int bm = blockIdx.y * 128, bn = blockIdx.x * 128;
  __shared__ bf16 As[128][64];   // unpadded: required by global_load_lds lane order
  __shared__ bf16 Bs[128][64];
  int t = threadIdx.x, wave = t >> 6, lane = t & 63;
  int wm = (wave >> 1) * 64, wn = (wave & 1) * 64;
  int fr = lane & 15, fo = (lane >> 4) * 8;
  int lrow = lane >> 3, lcol = (lane & 7) * 8;   // within an 8-row (1KB) chunk
  floatx4 acc[4][4];
  #pragma unroll
  for (int i = 0; i < 4; ++i)
    #pragma unroll
    for (int j = 0; j < 4; ++j) acc[i][j] = (floatx4){0.f, 0.f, 0.f, 0.f};

  for (int k0 = 0; k0 < K; k0 += 64) {
    #pragma unroll
    for (int c = 0; c < 4; ++c) {
      int chunk = wave * 4 + c;            // 16 chunks of 8 rows each
      int row = chunk * 8 + lrow;
      gll16(A  + (size_t)(bm + row) * K + k0 + lcol, &As[0][0] + chunk * 512);
      gll16(Wm + (size_t)(bn + row) * K + k0 + lcol, &Bs[0][0] + chunk * 512);
    }
    __syncthreads();
    #pragma unroll
    for (int ks = 0; ks < 2; ++ks) {
      short8 af[4], bfv[4];
      #pragma unroll
      for (int rt = 0; rt < 4; ++rt) af[rt]  = *(const short8*)&As[wm + rt * 16 + fr][ks * 32 + fo];
      #pragma unroll
      for (int ct = 0; ct < 4; ++ct) bfv[ct] = *(const short8*)&Bs[wn + ct * 16 + fr][ks * 32 + fo];
      #pragma unroll
      for (int rt = 0; rt < 4; ++rt)
        #pragma unroll
        for (int ct = 0; ct < 4; ++ct)
          acc[rt][ct] = MFMA16(af[rt], bfv[ct], acc[rt][ct]);
    }
    __syncthreads();
  }
  #pragma unroll
  for (int rt = 0; rt < 4; ++rt) {
    #pragma unroll
    for (int r = 0; r < 4; ++r) {
      int row = bm + wm + rt * 16 + (lane >> 4) * 4 + r;
      #pragma unroll
      for (int ct = 0; ct < 4; ++ct) {
        int col = bn + wn + ct * 16 + fr;
        float v = acc[rt][ct][r] + (bias ? bias[col] : 0.f);
        if (relu) v = fmaxf(v, 0.f);
        if (Cf) Cf[cbase + (size_t)row * N + col] = v;
        if (Cb) Cb[cbase + (size_t)row * N + col] = f2b(v);
      }
    }
  }
}

// ---------------- BatchNorm stats
__global__ __launch_bounds__(256) void bn_stats(const float* __restrict__ x, float* __restrict__ st)
{
  int c = blockIdx.x;
  float s = 0.f, q = 0.f;
  for (int r = threadIdx.x; r < Nz; r += 256) {
    float v = x[(size_t)r * Ez + c];
    s += v; q += v * v;
  }
  for (int o = 32; o; o >>= 1) { s += __shfl_down(s, o); q += __shfl_down(q, o); }
  __shared__ float shs[4], shq[4];
  int w = threadIdx.x >> 6;
  if ((threadIdx.x & 63) == 0) { shs[w] = s; shq[w] = q; }
  __syncthreads();
  if (threadIdx.x == 0) {
    s = shs[0] + shs[1] + shs[2] + shs[3];
    q = shq[0] + shq[1] + shq[2] + shq[3];
    float mu = s / (float)Nz;
    float var = q / (float)Nz - mu * mu;
    st[c] = mu;
    st[Ez + c] = rsqrtf(var + EPSf);
  }
}

// ---------------- BN apply + positional encoding
__global__ __launch_bounds__(256) void bn_apply_pe(const float* __restrict__ x0,
    const float* __restrict__ st, const float* __restrict__ g,
    const float* __restrict__ b, float* __restrict__ x, bf16* __restrict__ xb)
{
  int idx = blockIdx.x * 256 + threadIdx.x;
  int c = idx & (Ez - 1);
  int r = idx >> 9;
  int s = r & (Sz - 1);
  float dt = expf((float)(c & ~1) * (-9.210340371976184f / (float)Ez));
  float ang = (float)s * dt;
  float pe = (c & 1) ? cosf(ang) : sinf(ang);
  float mu = st[c], rs = st[Ez + c];
  float v = (x0[idx] - mu) * rs * g[c] + b[c] + pe;
  x[idx] = v;
  xb[idx] = f2b(v);
}

// ---------------- distance bias -> bf16
__global__ __launch_bounds__(256) void dist_bias_k(const float* __restrict__ dist,
    const float* __restrict__ dsc, bf16* __restrict__ db)
{
  size_t base = (size_t)blockIdx.x * Sz;
  float m = -1e30f;
  for (int j = threadIdx.x; j < Sz; j += 256) m = fmaxf(m, dist[base + j]);
  for (int o = 32; o; o >>= 1) m = fmaxf(m, __shfl_down(m, o));
  __shared__ float sh[4];
  if ((threadIdx.x & 63) == 0) sh[threadIdx.x >> 6] = m;
  __syncthreads();
  m = fmaxf(fmaxf(sh[0], sh[1]), fmaxf(sh[2], sh[3]));
  float sc = dsc[0];
  float inv = 1.f / m;
  for (int j = threadIdx.x; j < Sz; j += 256)
    db[base + j] = f2b(expf(sc * (1.f - dist[base + j] * inv)));
}

// ---------------- transpose xb [B*S,E] -> xT [B][E][S]
__global__ __launch_bounds__(256) void transpose_xb(const bf16* __restrict__ xb,
    bf16* __restrict__ xT)
{
  int b = blockIdx.z, e0 = blockIdx.y * 32, s0 = blockIdx.x * 32;
  __shared__ bf16 T[32][40];
  int t = threadIdx.x, row = t >> 3, c = t & 7;
  *(ushort4*)&T[row][c * 4] = *(const ushort4*)(xb + (size_t)(b * Sz + s0 + row) * Ez + e0 + c * 4);
  __syncthreads();
  ushort4 v;
  unsigned short* vp = (unsigned short*)&v;
  #pragma unroll
  for (int i = 0; i < 4; ++i) vp[i] = *(const unsigned short*)&T[c * 4 + i][row];
  *(ushort4*)(xT + ((size_t)b * Ez + e0 + row) * Sz + s0 + c * 4) = v;
}

// ---------------- attention Z: zinv[b,h,q] = 1/sum_k exp(q.k/8)
// register-direct MFMA fragments, no LDS, no barriers. m==0 is safe: scores
// are O(1) (LN'd activations, 0.02-scale weights), far from exp overflow.
__global__ __launch_bounds__(256) void attn_stats3(const bf16* __restrict__ qk,
    float* __restrict__ zinv)
{
  int qt = blockIdx.x, h = blockIdx.y, b = blockIdx.z;
  int q0 = qt * 64;
  int t = threadIdx.x, wave = t >> 6, lane = t & 63;
  int fr = lane & 15, fq = lane >> 4, fo = fq * 8;
  const bf16* qp = qk + (size_t)(b * Sz + q0 + wave * 16 + fr) * 1024 + h * 64;
  short8 aq0 = *(const short8*)(qp + fo);
  short8 aq1 = *(const short8*)(qp + 32 + fo);
  const bf16* kbase = qk + (size_t)(b * Sz) * 1024 + 512 + h * 64;
  float z[4] = {0.f, 0.f, 0.f, 0.f};
  for (int k0 = 0; k0 < Sz; k0 += 64) {
    #pragma unroll
    for (int ct = 0; ct < 4; ++ct) {
      const bf16* kp = kbase + (size_t)(k0 + ct * 16 + fr) * 1024;
      short8 b0 = *(const short8*)(kp + fo);
      short8 b1 = *(const short8*)(kp + 32 + fo);
      floatx4 s = (floatx4){0.f, 0.f, 0.f, 0.f};
      s = MFMA16(aq0, b0, s);
      s = MFMA16(aq1, b1, s);
      #pragma unroll
      for (int r = 0; r < 4; ++r) z[r] += __expf(s[r] * 0.125f);
    }
  }
  #pragma unroll
  for (int r = 0; r < 4; ++r) {
    #pragma unroll
    for (int o = 1; o < 16; o <<= 1) z[r] += __shfl_xor(z[r], o, 16);
  }
  if (fr == 0) {
    #pragma unroll
    for (int r = 0; r < 4; ++r)
      zinv[(size_t)(b * Hz + h) * Sz + q0 + wave * 16 + fq * 4 + r] = 1.f / z[r];
  }
}

// ---------------- scores: aw[b,q,k] = (1/H Σ_h exp(s_h)*zinv_h) * db  (bf16)
// register-direct fragments, no LDS. Also writes row-sum partials denp[.][kb].
__global__ __launch_bounds__(256) void scores3(const bf16* __restrict__ qk,
    const bf16* __restrict__ db, const float* __restrict__ zinv,
    bf16* __restrict__ aw, float* __restrict__ denp)
{
  int kb = blockIdx.x * 64, qb = blockIdx.y * 64, b = blockIdx.z;
  int t = threadIdx.x, wave = t >> 6, lane = t & 63;
  int fr = lane & 15, fq = lane >> 4, fo = fq * 8;
  int qrow = qb + wave * 16;           // this wave's 16 q-rows
  float zi[8][4];
  #pragma unroll
  for (int h = 0; h < 8; ++h)
    #pragma unroll
    for (int r = 0; r < 4; ++r)
      zi[h][r] = zinv[(size_t)(b * Hz + h) * Sz + qrow + fq * 4 + r];

  float p[4][4];   // [ct][r]
  #pragma unroll
  for (int ct = 0; ct < 4; ++ct)
    #pragma unroll
    for (int r = 0; r < 4; ++r) p[ct][r] = 0.f;

  for (int h = 0; h < Hz; ++h) {
    const bf16* qp = qk + (size_t)(b * Sz + qrow + fr) * 1024 + h * 64;
    short8 aq0 = *(const short8*)(qp + fo);
    short8 aq1 = *(const short8*)(qp + 32 + fo);
    const bf16* kbase = qk + (size_t)(b * Sz + kb) * 1024 + 512 + h * 64;
    #pragma unroll
    for (int ct = 0; ct < 4; ++ct) {
      const bf16* kp = kbase + (size_t)(ct * 16 + fr) * 1024;
      short8 b0 = *(const short8*)(kp + fo);
      short8 b1 = *(const short8*)(kp + 32 + fo);
      floatx4 s = (floatx4){0.f, 0.f, 0.f, 0.f};
      s = MFMA16(aq0, b0, s);
      s = MFMA16(aq1, b1, s);
      #pragma unroll
      for (int r = 0; r < 4; ++r)
        p[ct][r] += __expf(s[r] * 0.125f) * zi[h][r];
    }
  }
  float dsum[4] = {0.f, 0.f, 0.f, 0.f};
  #pragma unroll
  for (int r = 0; r < 4; ++r) {
    int q = qrow + fq * 4 + r;
    #pragma unroll
    for (int ct = 0; ct < 4; ++ct) {
      size_t off = (size_t)(b * Sz + q) * Sz + kb + ct * 16 + fr;
      float v = p[ct][r] * 0.125f * b2f(db[off]);
      bf16 pb = f2b(v);
      aw[off] = pb;
      dsum[r] += b2f(pb);      // denominator from rounded value (matches PV input)
    }
    #pragma unroll
    for (int o = 1; o < 16; o <<= 1) dsum[r] += __shfl_xor(dsum[r], o, 16);
  }
  if (fr == 0) {
    #pragma unroll
    for (int r = 0; r < 4; ++r)
      denp[(size_t)(b * Sz + qrow + fq * 4 + r) * 16 + blockIdx.x] = dsum[r];
  }
}

// ---------------- denp [N][16] -> den [N]
__global__ __launch_bounds__(256) void den_sum(const float* __restrict__ denp,
    float* __restrict__ den)
{
  int i = blockIdx.x * 256 + threadIdx.x;
  float s = 0.f;
  #pragma unroll
  for (int j = 0; j < 16; ++j) s += denp[(size_t)i * 16 + j];
  den[i] = s;
}

// ---------------- residual add + LayerNorm; dly optionally scaled by 1/rowdiv[row]
__global__ __launch_bounds__(256) void add_ln(const float* __restrict__ xin,
    const float* __restrict__ dly, const float* __restrict__ rowdiv,
    const float* __restrict__ g, const float* __restrict__ bb,
    float* __restrict__ xout, bf16* __restrict__ xbout)
{
  size_t base = (size_t)blockIdx.x * Ez;
  int t = threadIdx.x;
  float sc = rowdiv ? (1.f / rowdiv[blockIdx.x]) : 1.f;
  float a0 = xin[base + t] + dly[base + t] * sc;
  float a1 = xin[base + t + 256] + dly[base + t + 256] * sc;
  float s = a0 + a1, q = a0 * a0 + a1 * a1;
  for (int o = 32; o; o >>= 1) { s += __shfl_down(s, o); q += __shfl_down(q, o); }
  __shared__ float shs[4], shq[4];
  if ((t & 63) == 0) { shs[t >> 6] = s; shq[t >> 6] = q; }
  __syncthreads();
  s = shs[0] + shs[1] + shs[2] + shs[3];
  q = shq[0] + shq[1] + shq[2] + shq[3];
  float mu = s * (1.f / Ez);
  float var = q * (1.f / Ez) - mu * mu;
  float rs = rsqrtf(var + EPSf);
  float v0 = (a0 - mu) * rs * g[t] + bb[t];
  float v1 = (a1 - mu) * rs * g[t + 256] + bb[t + 256];
  xout[base + t] = v0;
  xout[base + t + 256] = v1;
  xbout[base + t] = f2b(v0);
  xbout[base + t + 256] = f2b(v1);
}

extern "C" void kernel_launch(void* const* d_in, const int* in_sizes, int n_in,
                              void* d_out, int out_size, void* d_ws, size_t ws_size,
                              hipStream_t stream)
{
  const float* src        = (const float*)d_in[0];
  const float* distances  = (const float*)d_in[1];
  const float* proj_w     = (const float*)d_in[2];
  const float* proj_b     = (const float*)d_in[3];
  const float* bn_g       = (const float*)d_in[4];
  const float* bn_b       = (const float*)d_in[5];
  const float* in_proj_w  = (const float*)d_in[6];
  const float* in_proj_b  = (const float*)d_in[7];
  const float* dist_scale = (const float*)d_in[8];
  const float* lin1_w     = (const float*)d_in[9];
  const float* lin1_b     = (const float*)d_in[10];
  const float* lin2_w     = (const float*)d_in[11];
  const float* lin2_b     = (const float*)d_in[12];
  const float* n1_g       = (const float*)d_in[13];
  const float* n1_b       = (const float*)d_in[14];
  const float* n2_g       = (const float*)d_in[15];
  const float* n2_b       = (const float*)d_in[16];

  float* x = (float*)d_out;                      // fp32 activations [N,E]

  float* zinv  = (float*)d_ws;                   // B*H*S   = 65536
  float* denp  = zinv + 65536;                   // N*16    = 131072
  float* den   = denp + 131072;                  // N       = 8192
  float* bnst  = den + 8192;                     // 2*E
  float* aout  = bnst + 1024;                    // N*E fp32
  float* x0    = aout;                           // alias (pre-loop only)
  bf16* db_b = (bf16*)(aout + (size_t)Nz * Ez);  // B*S*S
  bf16* Rqk  = db_b + (size_t)Bz * Sz * Sz;      // union region: qk+aw | ff1
  bf16* qk   = Rqk;                              // N*1024
  bf16* aw   = Rqk + (size_t)Nz * 1024;          // B*S*S
  bf16* ff1  = Rqk;                              // N*FF (aliases qk+aw, disjoint lifetime)
  bf16* xb   = Rqk + (size_t)Nz * FFz;           // N*E
  bf16* xT   = xb + (size_t)Nz * Ez;             // B*E*S
  bf16* srcb = xT + (size_t)Bz * Ez * Sz;        // N*IN
  bf16* wpr  = srcb + (size_t)Nz * INz;          // E*IN
  bf16* wqk  = wpr + Ez * INz;                   // 1024*E
  bf16* wl1  = wqk + 1024 * Ez;                  // FF*E
  bf16* wl2  = wl1 + FFz * Ez;                   // E*FF

  cast_f2b<<<(Nz * INz) / 256, 256, 0, stream>>>(src, srcb, Nz * INz);
  cast_f2b<<<(Ez * INz + 255) / 256, 256, 0, stream>>>(proj_w, wpr, Ez * INz);
  cast_f2b<<<(1024 * Ez) / 256, 256, 0, stream>>>(in_proj_w, wqk, 1024 * Ez);
  cast_f2b<<<(FFz * Ez) / 256, 256, 0, stream>>>(lin1_w, wl1, FFz * Ez);
  cast_f2b<<<(Ez * FFz) / 256, 256, 0, stream>>>(lin2_w, wl2, Ez * FFz);

  gemm_bt<<<dim3(Ez / 128, Nz / 128), 256, 0, stream>>>(
      srcb, wpr, proj_b, x0, nullptr, Nz, Ez, INz, 0, 0, 0, 0);
  bn_stats<<<Ez, 256, 0, stream>>>(x0, bnst);
  bn_apply_pe<<<(Nz * Ez) / 256, 256, 0, stream>>>(x0, bnst, bn_g, bn_b, x, xb);
  dist_bias_k<<<Bz * Sz, 256, 0, stream>>>(distances, dist_scale, db_b);

  for (int l = 0; l < Lz; ++l) {
    transpose_xb<<<dim3(Sz / 32, Ez / 32, Bz), 256, 0, stream>>>(xb, xT);
    gemm_bt<<<dim3(1024 / 128, Nz / 128), 256, 0, stream>>>(
        xb, wqk, in_proj_b, nullptr, qk, Nz, 1024, Ez, 0, 0, 0, 0);
    attn_stats3<<<dim3(Sz / 64, Hz, Bz), 256, 0, stream>>>(qk, zinv);
    scores3<<<dim3(Sz / 64, Sz / 64, Bz), 256, 0, stream>>>(qk, db_b, zinv, aw, denp);
    den_sum<<<Nz / 256, 256, 0, stream>>>(denp, den);
    // PV: batched aw[b] @ xT[b]^T -> aout (renorm folded into add_ln)
    gemm_bt<<<dim3(Ez / 128, Sz / 128, Bz), 256, 0, stream>>>(
        aw, xT, nullptr, aout, nullptr, Sz, Ez, Sz,
        (long)Sz * Sz, (long)Ez * Sz, (long)Sz * Ez, 0);
    add_ln<<<Nz, 256, 0, stream>>>(x, aout, den, n1_g, n1_b, x, xb);
    gemm_bt<<<dim3(FFz / 128, Nz / 128), 256, 0, stream>>>(
        xb, wl1, lin1_b, nullptr, ff1, Nz, FFz, Ez, 0, 0, 0, 1);
    gemm_bt<<<dim3(Ez / 128, Nz / 128), 256, 0, stream>>>(
        ff1, wl2, lin2_b, aout, nullptr, Nz, Ez, FFz, 0, 0, 0, 0);
    add_ln<<<Nz, 256, 0, stream>>>(x, aout, nullptr, n2_g, n2_b, x, xb);
  }
}

// Round 7
// 1297.894 us; speedup vs baseline: 1.1682x; 1.1682x over previous
//
#include <hip/hip_runtime.h>
#include <hip/hip_bf16.h>
#include <math.h>

#define Bz 8
#define Sz 1024
#define INz 128
#define Ez 512
#define Hz 8
#define HDz 64
#define FFz 2048
#define Lz 4
#define Nz (Bz*Sz)   // 8192
#define EPSf 1e-5f

typedef __attribute__((ext_vector_type(8))) short short8;
typedef __attribute__((ext_vector_type(4))) float floatx4;
#define MFMA16(a,b,c) __builtin_amdgcn_mfma_f32_16x16x32_bf16(a,b,c,0,0,0)

typedef __hip_bfloat16 bf16;

__device__ inline float b2f(bf16 v) { return __bfloat162float(v); }
__device__ inline bf16 f2b(float v) { return __float2bfloat16(v); }

// async 16B/lane global->LDS copy. lds base must be wave-uniform; HW adds lane*16.
__device__ inline void gll16(const bf16* g, bf16* l) {
  __builtin_amdgcn_global_load_lds(
      (const __attribute__((address_space(1))) unsigned int*)g,
      (__attribute__((address_space(3))) unsigned int*)l, 16, 0, 0);
}

// ---------------- fp32 -> bf16 cast
__global__ __launch_bounds__(256) void cast_f2b(const float* __restrict__ in,
    bf16* __restrict__ out, int n)
{
  int i = blockIdx.x * 256 + threadIdx.x;
  if (i < n) out[i] = f2b(in[i]);
}

// ---------------- bf16 MFMA NT GEMM, m97-style async staging, batched
__global__ __launch_bounds__(256) void gemm_bt(
    const bf16* __restrict__ A, const bf16* __restrict__ Wm,
    const float* __restrict__ bias, float* __restrict__ Cf,
    bf16* __restrict__ Cb, int M, int N, int K,
    long sA, long sW, long sC, int relu)
{
  int z = blockIdx.z;
  A  += (size_t)z * sA;
  Wm += (size_t)z * sW;
  size_t cbase = (size_t)z * sC;
  int bm = blockIdx.y * 128, bn = blockIdx.x * 128;
  __shared__ bf16 As[128][64];   // unpadded: required by global_load_lds lane order
  __shared__ bf16 Bs[128][64];
  int t = threadIdx.x, wave = t >> 6, lane = t & 63;
  int wm = (wave >> 1) * 64, wn = (wave & 1) * 64;
  int fr = lane & 15, fo = (lane >> 4) * 8;
  int lrow = lane >> 3, lcol = (lane & 7) * 8;
  floatx4 acc[4][4];
  #pragma unroll
  for (int i = 0; i < 4; ++i)
    #pragma unroll
    for (int j = 0; j < 4; ++j) acc[i][j] = (floatx4){0.f, 0.f, 0.f, 0.f};

  for (int k0 = 0; k0 < K; k0 += 64) {
    #pragma unroll
    for (int c = 0; c < 4; ++c) {
      int chunk = wave * 4 + c;
      int row = chunk * 8 + lrow;
      gll16(A  + (size_t)(bm + row) * K + k0 + lcol, &As[0][0] + chunk * 512);
      gll16(Wm + (size_t)(bn + row) * K + k0 + lcol, &Bs[0][0] + chunk * 512);
    }
    __syncthreads();
    #pragma unroll
    for (int ks = 0; ks < 2; ++ks) {
      short8 af[4], bfv[4];
      #pragma unroll
      for (int rt = 0; rt < 4; ++rt) af[rt]  = *(const short8*)&As[wm + rt * 16 + fr][ks * 32 + fo];
      #pragma unroll
      for (int ct = 0; ct < 4; ++ct) bfv[ct] = *(const short8*)&Bs[wn + ct * 16 + fr][ks * 32 + fo];
      #pragma unroll
      for (int rt = 0; rt < 4; ++rt)
        #pragma unroll
        for (int ct = 0; ct < 4; ++ct)
          acc[rt][ct] = MFMA16(af[rt], bfv[ct], acc[rt][ct]);
    }
    __syncthreads();
  }
  #pragma unroll
  for (int rt = 0; rt < 4; ++rt) {
    #pragma unroll
    for (int r = 0; r < 4; ++r) {
      int row = bm + wm + rt * 16 + (lane >> 4) * 4 + r;
      #pragma unroll
      for (int ct = 0; ct < 4; ++ct) {
        int col = bn + wn + ct * 16 + fr;
        float v = acc[rt][ct][r] + (bias ? bias[col] : 0.f);
        if (relu) v = fmaxf(v, 0.f);
        if (Cf) Cf[cbase + (size_t)row * N + col] = v;
        if (Cb) Cb[cbase + (size_t)row * N + col] = f2b(v);
      }
    }
  }
}

// ---------------- BatchNorm stats
__global__ __launch_bounds__(256) void bn_stats(const float* __restrict__ x, float* __restrict__ st)
{
  int c = blockIdx.x;
  float s = 0.f, q = 0.f;
  for (int r = threadIdx.x; r < Nz; r += 256) {
    float v = x[(size_t)r * Ez + c];
    s += v; q += v * v;
  }
  for (int o = 32; o; o >>= 1) { s += __shfl_down(s, o); q += __shfl_down(q, o); }
  __shared__ float shs[4], shq[4];
  int w = threadIdx.x >> 6;
  if ((threadIdx.x & 63) == 0) { shs[w] = s; shq[w] = q; }
  __syncthreads();
  if (threadIdx.x == 0) {
    s = shs[0] + shs[1] + shs[2] + shs[3];
    q = shq[0] + shq[1] + shq[2] + shq[3];
    float mu = s / (float)Nz;
    float var = q / (float)Nz - mu * mu;
    st[c] = mu;
    st[Ez + c] = rsqrtf(var + EPSf);
  }
}

// ---------------- BN apply + positional encoding
__global__ __launch_bounds__(256) void bn_apply_pe(const float* __restrict__ x0,
    const float* __restrict__ st, const float* __restrict__ g,
    const float* __restrict__ b, float* __restrict__ x, bf16* __restrict__ xb)
{
  int idx = blockIdx.x * 256 + threadIdx.x;
  int c = idx & (Ez - 1);
  int r = idx >> 9;
  int s = r & (Sz - 1);
  float dt = expf((float)(c & ~1) * (-9.210340371976184f / (float)Ez));
  float ang = (float)s * dt;
  float pe = (c & 1) ? cosf(ang) : sinf(ang);
  float mu = st[c], rs = st[Ez + c];
  float v = (x0[idx] - mu) * rs * g[c] + b[c] + pe;
  x[idx] = v;
  xb[idx] = f2b(v);
}

// ---------------- distance bias -> bf16
__global__ __launch_bounds__(256) void dist_bias_k(const float* __restrict__ dist,
    const float* __restrict__ dsc, bf16* __restrict__ db)
{
  size_t base = (size_t)blockIdx.x * Sz;
  float m = -1e30f;
  for (int j = threadIdx.x; j < Sz; j += 256) m = fmaxf(m, dist[base + j]);
  for (int o = 32; o; o >>= 1) m = fmaxf(m, __shfl_down(m, o));
  __shared__ float sh[4];
  if ((threadIdx.x & 63) == 0) sh[threadIdx.x >> 6] = m;
  __syncthreads();
  m = fmaxf(fmaxf(sh[0], sh[1]), fmaxf(sh[2], sh[3]));
  float sc = dsc[0];
  float inv = 1.f / m;
  for (int j = threadIdx.x; j < Sz; j += 256)
    db[base + j] = f2b(expf(sc * (1.f - dist[base + j] * inv)));
}

// ---------------- transpose xb [B*S,E] -> xT [B][E][S]
__global__ __launch_bounds__(256) void transpose_xb(const bf16* __restrict__ xb,
    bf16* __restrict__ xT)
{
  int b = blockIdx.z, e0 = blockIdx.y * 32, s0 = blockIdx.x * 32;
  __shared__ bf16 T[32][40];
  int t = threadIdx.x, row = t >> 3, c = t & 7;
  *(ushort4*)&T[row][c * 4] = *(const ushort4*)(xb + (size_t)(b * Sz + s0 + row) * Ez + e0 + c * 4);
  __syncthreads();
  ushort4 v;
  unsigned short* vp = (unsigned short*)&v;
  #pragma unroll
  for (int i = 0; i < 4; ++i) vp[i] = *(const unsigned short*)&T[c * 4 + i][row];
  *(ushort4*)(xT + ((size_t)b * Ez + e0 + row) * Sz + s0 + c * 4) = v;
}

// ---------------- stats pass: zpart[(b,h,q)][oct] = sum_{k in oct} exp(q.k/8)
// Q frags hoisted to regs (all 8 heads); K staged per 32-row chunk in padded
// LDS via coalesced float4 loads (frag reads: 2-way bank alias = free).
// m==0 safe: LN'd activations x 0.02-scale weights -> |s| = O(1).
__global__ __launch_bounds__(256) void stats_pass(const bf16* __restrict__ qk,
    float* __restrict__ zpart)
{
  int kOct = blockIdx.x, qt = blockIdx.y, b = blockIdx.z;
  int qb = qt * 64, kb0 = kOct * 128;
  __shared__ bf16 Ks[32][520];
  int t = threadIdx.x, wave = t >> 6, lane = t & 63;
  int fr = lane & 15, fq = lane >> 4;
  int qrow = qb + wave * 16;
  const bf16* qp0 = qk + (size_t)(b * Sz + qrow + fr) * 1024;
  short8 aq[8][2];
  #pragma unroll
  for (int h = 0; h < 8; ++h) {
    aq[h][0] = *(const short8*)(qp0 + h * 64 + fq * 8);
    aq[h][1] = *(const short8*)(qp0 + h * 64 + 32 + fq * 8);
  }
  float z[8][4];
  #pragma unroll
  for (int h = 0; h < 8; ++h)
    #pragma unroll
    for (int r = 0; r < 4; ++r) z[h][r] = 0.f;

  for (int c = 0; c < 4; ++c) {
    #pragma unroll
    for (int i = 0; i < 8; ++i) {
      int idx = i * 256 + t, row = idx >> 6, c4 = idx & 63;
      *(float4*)&Ks[row][c4 * 8] =
        *(const float4*)(qk + (size_t)(b * Sz + kb0 + c * 32 + row) * 1024 + 512 + c4 * 8);
    }
    __syncthreads();
    #pragma unroll
    for (int h = 0; h < 8; ++h)
      #pragma unroll
      for (int ct = 0; ct < 2; ++ct) {
        short8 b0 = *(const short8*)&Ks[ct * 16 + fr][h * 64 + fq * 8];
        short8 b1 = *(const short8*)&Ks[ct * 16 + fr][h * 64 + 32 + fq * 8];
        floatx4 s = (floatx4){0.f, 0.f, 0.f, 0.f};
        s = MFMA16(aq[h][0], b0, s);
        s = MFMA16(aq[h][1], b1, s);
        #pragma unroll
        for (int r = 0; r < 4; ++r) z[h][r] += __expf(s[r] * 0.125f);
      }
    __syncthreads();
  }
  #pragma unroll
  for (int h = 0; h < 8; ++h)
    #pragma unroll
    for (int r = 0; r < 4; ++r) {
      #pragma unroll
      for (int o = 1; o < 16; o <<= 1) z[h][r] += __shfl_xor(z[h][r], o, 16);
    }
  if (fr == 0) {
    #pragma unroll
    for (int h = 0; h < 8; ++h)
      #pragma unroll
      for (int r = 0; r < 4; ++r)
        zpart[((size_t)(b * Hz + h) * Sz + qrow + fq * 4 + r) * 8 + kOct] = z[h][r];
  }
}

// ---------------- zpart [BHS][8] -> zinv [BHS]
__global__ __launch_bounds__(256) void zred(const float* __restrict__ zpart,
    float* __restrict__ zinv)
{
  int i = blockIdx.x * 256 + threadIdx.x;
  float s = 0.f;
  #pragma unroll
  for (int j = 0; j < 8; ++j) s += zpart[(size_t)i * 8 + j];
  zinv[i] = 1.f / s;
}

// ---------------- scores pass: aw = (1/H Σ_h exp(s_h)·zinv_h) · db (bf16)
// same staging structure as stats_pass; writes row-sum partials denp[.][oct].
__global__ __launch_bounds__(256) void scores_pass(const bf16* __restrict__ qk,
    const bf16* __restrict__ db, const float* __restrict__ zinv,
    bf16* __restrict__ aw, float* __restrict__ denp)
{
  int kOct = blockIdx.x, qt = blockIdx.y, b = blockIdx.z;
  int qb = qt * 64, kb0 = kOct * 128;
  __shared__ bf16 Ks[32][520];
  int t = threadIdx.x, wave = t >> 6, lane = t & 63;
  int fr = lane & 15, fq = lane >> 4;
  int qrow = qb + wave * 16;
  const bf16* qp0 = qk + (size_t)(b * Sz + qrow + fr) * 1024;
  short8 aq[8][2];
  #pragma unroll
  for (int h = 0; h < 8; ++h) {
    aq[h][0] = *(const short8*)(qp0 + h * 64 + fq * 8);
    aq[h][1] = *(const short8*)(qp0 + h * 64 + 32 + fq * 8);
  }
  float zi[8][4];
  #pragma unroll
  for (int h = 0; h < 8; ++h)
    #pragma unroll
    for (int r = 0; r < 4; ++r)
      zi[h][r] = zinv[(size_t)(b * Hz + h) * Sz + qrow + fq * 4 + r];

  float dsum[4] = {0.f, 0.f, 0.f, 0.f};

  for (int c = 0; c < 4; ++c) {
    #pragma unroll
    for (int i = 0; i < 8; ++i) {
      int idx = i * 256 + t, row = idx >> 6, c4 = idx & 63;
      *(float4*)&Ks[row][c4 * 8] =
        *(const float4*)(qk + (size_t)(b * Sz + kb0 + c * 32 + row) * 1024 + 512 + c4 * 8);
    }
    __syncthreads();
    float p[2][4];
    #pragma unroll
    for (int ct = 0; ct < 2; ++ct)
      #pragma unroll
      for (int r = 0; r < 4; ++r) p[ct][r] = 0.f;
    #pragma unroll
    for (int h = 0; h < 8; ++h)
      #pragma unroll
      for (int ct = 0; ct < 2; ++ct) {
        short8 b0 = *(const short8*)&Ks[ct * 16 + fr][h * 64 + fq * 8];
        short8 b1 = *(const short8*)&Ks[ct * 16 + fr][h * 64 + 32 + fq * 8];
        floatx4 s = (floatx4){0.f, 0.f, 0.f, 0.f};
        s = MFMA16(aq[h][0], b0, s);
        s = MFMA16(aq[h][1], b1, s);
        #pragma unroll
        for (int r = 0; r < 4; ++r)
          p[ct][r] += __expf(s[r] * 0.125f) * zi[h][r];
      }
    // epilogue for this 64q x 32k chunk
    #pragma unroll
    for (int r = 0; r < 4; ++r) {
      int q = qrow + fq * 4 + r;
      #pragma unroll
      for (int ct = 0; ct < 2; ++ct) {
        size_t off = (size_t)(b * Sz + q) * Sz + kb0 + c * 32 + ct * 16 + fr;
        float v = p[ct][r] * 0.125f * b2f(db[off]);
        bf16 pb = f2b(v);
        aw[off] = pb;
        dsum[r] += b2f(pb);   // denominator from rounded value (matches PV input)
      }
    }
    __syncthreads();
  }
  #pragma unroll
  for (int r = 0; r < 4; ++r) {
    #pragma unroll
    for (int o = 1; o < 16; o <<= 1) dsum[r] += __shfl_xor(dsum[r], o, 16);
  }
  if (fr == 0) {
    #pragma unroll
    for (int r = 0; r < 4; ++r)
      denp[(size_t)(b * Sz + qrow + fq * 4 + r) * 8 + kOct] = dsum[r];
  }
}

// ---------------- denp [N][8] -> den [N]
__global__ __launch_bounds__(256) void den_sum(const float* __restrict__ denp,
    float* __restrict__ den)
{
  int i = blockIdx.x * 256 + threadIdx.x;
  float s = 0.f;
  #pragma unroll
  for (int j = 0; j < 8; ++j) s += denp[(size_t)i * 8 + j];
  den[i] = s;
}

// ---------------- residual add + LayerNorm; dly optionally scaled by 1/rowdiv[row]
__global__ __launch_bounds__(256) void add_ln(const float* __restrict__ xin,
    const float* __restrict__ dly, const float* __restrict__ rowdiv,
    const float* __restrict__ g, const float* __restrict__ bb,
    float* __restrict__ xout, bf16* __restrict__ xbout)
{
  size_t base = (size_t)blockIdx.x * Ez;
  int t = threadIdx.x;
  float sc = rowdiv ? (1.f / rowdiv[blockIdx.x]) : 1.f;
  float a0 = xin[base + t] + dly[base + t] * sc;
  float a1 = xin[base + t + 256] + dly[base + t + 256] * sc;
  float s = a0 + a1, q = a0 * a0 + a1 * a1;
  for (int o = 32; o; o >>= 1) { s += __shfl_down(s, o); q += __shfl_down(q, o); }
  __shared__ float shs[4], shq[4];
  if ((t & 63) == 0) { shs[t >> 6] = s; shq[t >> 6] = q; }
  __syncthreads();
  s = shs[0] + shs[1] + shs[2] + shs[3];
  q = shq[0] + shq[1] + shq[2] + shq[3];
  float mu = s * (1.f / Ez);
  float var = q * (1.f / Ez) - mu * mu;
  float rs = rsqrtf(var + EPSf);
  float v0 = (a0 - mu) * rs * g[t] + bb[t];
  float v1 = (a1 - mu) * rs * g[t + 256] + bb[t + 256];
  xout[base + t] = v0;
  xout[base + t + 256] = v1;
  xbout[base + t] = f2b(v0);
  xbout[base + t + 256] = f2b(v1);
}

extern "C" void kernel_launch(void* const* d_in, const int* in_sizes, int n_in,
                              void* d_out, int out_size, void* d_ws, size_t ws_size,
                              hipStream_t stream)
{
  const float* src        = (const float*)d_in[0];
  const float* distances  = (const float*)d_in[1];
  const float* proj_w     = (const float*)d_in[2];
  const float* proj_b     = (const float*)d_in[3];
  const float* bn_g       = (const float*)d_in[4];
  const float* bn_b       = (const float*)d_in[5];
  const float* in_proj_w  = (const float*)d_in[6];
  const float* in_proj_b  = (const float*)d_in[7];
  const float* dist_scale = (const float*)d_in[8];
  const float* lin1_w     = (const float*)d_in[9];
  const float* lin1_b     = (const float*)d_in[10];
  const float* lin2_w     = (const float*)d_in[11];
  const float* lin2_b     = (const float*)d_in[12];
  const float* n1_g       = (const float*)d_in[13];
  const float* n1_b       = (const float*)d_in[14];
  const float* n2_g       = (const float*)d_in[15];
  const float* n2_b       = (const float*)d_in[16];

  float* x = (float*)d_out;                      // fp32 activations [N,E]

  float* zpart = (float*)d_ws;                   // B*H*S*8 = 524288
  float* zinv  = zpart + 524288;                 // B*H*S   = 65536
  float* denp  = zinv + 65536;                   // N*8     = 65536
  float* den   = denp + 65536;                   // N       = 8192
  float* bnst  = den + 8192;                     // 2*E
  float* aout  = bnst + 1024;                    // N*E fp32
  float* x0    = aout;                           // alias (pre-loop only)
  bf16* db_b = (bf16*)(aout + (size_t)Nz * Ez);  // B*S*S
  bf16* Rqk  = db_b + (size_t)Bz * Sz * Sz;      // union region: qk+aw | ff1
  bf16* qk   = Rqk;                              // N*1024
  bf16* aw   = Rqk + (size_t)Nz * 1024;          // B*S*S
  bf16* ff1  = Rqk;                              // N*FF (aliases qk+aw, disjoint lifetime)
  bf16* xb   = Rqk + (size_t)Nz * FFz;           // N*E
  bf16* xT   = xb + (size_t)Nz * Ez;             // B*E*S
  bf16* srcb = xT + (size_t)Bz * Ez * Sz;        // N*IN
  bf16* wpr  = srcb + (size_t)Nz * INz;          // E*IN
  bf16* wqk  = wpr + Ez * INz;                   // 1024*E
  bf16* wl1  = wqk + 1024 * Ez;                  // FF*E
  bf16* wl2  = wl1 + FFz * Ez;                   // E*FF

  cast_f2b<<<(Nz * INz) / 256, 256, 0, stream>>>(src, srcb, Nz * INz);
  cast_f2b<<<(Ez * INz + 255) / 256, 256, 0, stream>>>(proj_w, wpr, Ez * INz);
  cast_f2b<<<(1024 * Ez) / 256, 256, 0, stream>>>(in_proj_w, wqk, 1024 * Ez);
  cast_f2b<<<(FFz * Ez) / 256, 256, 0, stream>>>(lin1_w, wl1, FFz * Ez);
  cast_f2b<<<(Ez * FFz) / 256, 256, 0, stream>>>(lin2_w, wl2, Ez * FFz);

  gemm_bt<<<dim3(Ez / 128, Nz / 128), 256, 0, stream>>>(
      srcb, wpr, proj_b, x0, nullptr, Nz, Ez, INz, 0, 0, 0, 0);
  bn_stats<<<Ez, 256, 0, stream>>>(x0, bnst);
  bn_apply_pe<<<(Nz * Ez) / 256, 256, 0, stream>>>(x0, bnst, bn_g, bn_b, x, xb);
  dist_bias_k<<<Bz * Sz, 256, 0, stream>>>(distances, dist_scale, db_b);

  for (int l = 0; l < Lz; ++l) {
    transpose_xb<<<dim3(Sz / 32, Ez / 32, Bz), 256, 0, stream>>>(xb, xT);
    gemm_bt<<<dim3(1024 / 128, Nz / 128), 256, 0, stream>>>(
        xb, wqk, in_proj_b, nullptr, qk, Nz, 1024, Ez, 0, 0, 0, 0);
    stats_pass<<<dim3(8, Sz / 64, Bz), 256, 0, stream>>>(qk, zpart);
    zred<<<(Bz * Hz * Sz) / 256, 256, 0, stream>>>(zpart, zinv);
    scores_pass<<<dim3(8, Sz / 64, Bz), 256, 0, stream>>>(qk, db_b, zinv, aw, denp);
    den_sum<<<Nz / 256, 256, 0, stream>>>(denp, den);
    // PV: batched aw[b] @ xT[b]^T -> aout (renorm folded into add_ln)
    gemm_bt<<<dim3(Ez / 128, Sz / 128, Bz), 256, 0, stream>>>(
        aw, xT, nullptr, aout, nullptr, Sz, Ez, Sz,
        (long)Sz * Sz, (long)Ez * Sz, (long)Sz * Ez, 0);
    add_ln<<<Nz, 256, 0, stream>>>(x, aout, den, n1_g, n1_b, x, xb);
    gemm_bt<<<dim3(FFz / 128, Nz / 128), 256, 0, stream>>>(
        xb, wl1, lin1_b, nullptr, ff1, Nz, FFz, Ez, 0, 0, 0, 1);
    gemm_bt<<<dim3(Ez / 128, Nz / 128), 256, 0, stream>>>(
        ff1, wl2, lin2_b, aout, nullptr, Nz, Ez, FFz, 0, 0, 0, 0);
    add_ln<<<Nz, 256, 0, stream>>>(x, aout, nullptr, n2_g, n2_b, x, xb);
  }
}